// Round 4
// baseline (84.286 us; speedup 1.0000x reference)
//
#include <hip/hip_runtime.h>
#include <cstdint>
#include <cstddef>

#define NCLS 80
#define KTOP 10
#define NG   20
#define NB   32
#define A0   6400
#define A1   1600
#define A2   400
#define ATOT 8400
#define EPSF 1e-9f
#define CAP  512      // max in-box anchors per (b,g,level): boxes <=136px -> <=18^2=324

// ---------------------------------------------------------------------------
// Init: zero candidate counters, loss accumulators, and the done-ticket.
// (mask zeroing is folded into phase1 — one thread per mask word.)
// ---------------------------------------------------------------------------
__global__ __launch_bounds__(256) void init_small(int* __restrict__ cnt,
                                                  float* __restrict__ lossAcc,
                                                  int* __restrict__ cntAcc,
                                                  int* __restrict__ done)
{
    for (int i = threadIdx.x; i < NB * NG * 3; i += 256) cnt[i] = 0;
    if (threadIdx.x == 0) { *lossAcc = 0.f; *cntAcc = 0; *done = 0; }
}

// ---------------------------------------------------------------------------
// Phase 1: per (b, anchor): zero mask word; in-box test FIRST (cheap: reg +
// broadcast boxes); only anchors inside >=1 gt box load the 80-class row and
// do the softmax. Appends (val, a) candidates per (b,g,level) list.
// ---------------------------------------------------------------------------
__global__ __launch_bounds__(256) void phase1_metric(
    const float* __restrict__ cls0, const float* __restrict__ reg0,
    const float* __restrict__ cls1, const float* __restrict__ reg1,
    const float* __restrict__ cls2, const float* __restrict__ reg2,
    const float* __restrict__ anchors, const float* __restrict__ gtb,
    const int* __restrict__ gtl,
    float* __restrict__ logZ, int* __restrict__ cnt,
    float* __restrict__ cval, int* __restrict__ cidx,
    uint32_t* __restrict__ mask)
{
    int t = blockIdx.x * 256 + threadIdx.x;
    if (t >= NB * ATOT) return;
    mask[t] = 0;                       // free coalesced zeroing (replaces 40us memset)
    int b = t / ATOT, a = t % ATOT;

    const float* cls; const float* reg; int off, A, lvl; float stride;
    if (a < A0)           { cls = cls0; reg = reg0; off = 0;     A = A0; lvl = 0; stride = 8.f;  }
    else if (a < A0 + A1) { cls = cls1; reg = reg1; off = A0;    A = A1; lvl = 1; stride = 16.f; }
    else                  { cls = cls2; reg = reg2; off = A0+A1; A = A2; lvl = 2; stride = 32.f; }
    int al = a - off;

    float ax = anchors[2 * a]     * stride;
    float ay = anchors[2 * a + 1] * stride;

    // in-box test over all 20 gts (broadcast loads, L1/L2 hit)
    const float4* gb4 = reinterpret_cast<const float4*>(gtb + (size_t)b * NG * 4);
    uint32_t ingMask = 0;
    #pragma unroll
    for (int g = 0; g < NG; ++g) {
        float4 gv = gb4[g];
        bool ing = (ax - gv.x > EPSF) && (ay - gv.y > EPSF) &&
                   (gv.z - ax > EPSF) && (gv.w - ay > EPSF);
        if (ing) ingMask |= (1u << g);
    }
    if (!ingMask) return;   // ~75% of anchors: skip the 320B cls row entirely

    // predicted box
    float4 rr = *reinterpret_cast<const float4*>(reg + ((size_t)b * A + al) * 4);
    float px1 = ax - rr.x * stride, py1 = ay - rr.y * stride;
    float px2 = ax + rr.z * stride, py2 = ay + rr.w * stride;
    float area1 = (px2 - px1) * (py2 - py1);

    // softmax stats: 20 aligned float4 loads, kept in registers
    const float* crow = cls + ((size_t)b * A + al) * NCLS;
    const float4* crow4 = reinterpret_cast<const float4*>(crow);
    float r[NCLS];
    float m = -1e30f;
    #pragma unroll
    for (int j = 0; j < NCLS / 4; ++j) {
        float4 v = crow4[j];
        r[4*j+0] = v.x; r[4*j+1] = v.y; r[4*j+2] = v.z; r[4*j+3] = v.w;
        m = fmaxf(m, fmaxf(fmaxf(v.x, v.y), fmaxf(v.z, v.w)));
    }
    float s = 0.f;
    #pragma unroll
    for (int c = 0; c < NCLS; ++c) s += __expf(r[c] - m);
    float lz = m + __logf(s);
    logZ[(size_t)b * ATOT + a] = lz;

    const int* gl = gtl + b * NG;

    uint32_t mm = ingMask;
    while (mm) {
        int g = __ffs(mm) - 1; mm &= mm - 1;
        float4 gv = gb4[g];
        float ltx = fmaxf(px1, gv.x), lty = fmaxf(py1, gv.y);
        float rbx = fminf(px2, gv.z), rby = fminf(py2, gv.w);
        float w = fmaxf(rbx - ltx, 0.f), h = fmaxf(rby - lty, 0.f);
        float inter = w * h;
        float area2 = (gv.z - gv.x) * (gv.w - gv.y);
        float iou = inter / (area1 + area2 - inter + EPSF);
        float sc = __expf(crow[gl[g]] - lz);      // softmax score at gt label (L1-hot row)
        float i2 = iou * iou;
        float met = sc * (i2 * i2 * i2);          // score^1 * iou^6
        if (met > EPSF) {
            int list = (b * NG + g) * 3 + lvl;
            int slot = atomicAdd(&cnt[list], 1);
            if (slot < CAP) {
                cval[(size_t)list * CAP + slot] = met;
                cidx[(size_t)list * CAP + slot] = a;
            }
        }
    }
}

// ---------------------------------------------------------------------------
// Phase 2: exact top-10 per (b,g,level) over the compacted candidate list.
// Sort key = (val_bits << 32) | (ATOT - a): max key == (val desc, idx asc),
// identical tie-break to jax.lax.top_k. All candidates are > EPS by
// construction, so n<=KTOP means all are selected.
// ---------------------------------------------------------------------------
__global__ __launch_bounds__(64) void phase2_topk(
    const int* __restrict__ cnt, const float* __restrict__ cval,
    const int* __restrict__ cidx, uint32_t* __restrict__ mask)
{
    int id = blockIdx.x;            // (b*NG+g)*3 + lvl
    int bg = id / 3;
    int b = bg / NG, g = bg % NG;
    uint32_t bit = 1u << g;
    int lane = threadIdx.x;

    int n = cnt[id]; if (n > CAP) n = CAP;
    if (n == 0) return;

    const float* v  = cval + (size_t)id * CAP;
    const int*   ix = cidx + (size_t)id * CAP;

    if (n <= KTOP) {
        for (int i = lane; i < n; i += 64)
            atomicOr(&mask[(size_t)b * ATOT + ix[i]], bit);
        return;
    }

    __shared__ unsigned long long key[CAP];
    for (int i = lane; i < n; i += 64) {
        uint32_t vb = __float_as_uint(v[i]);                 // val > 0 -> monotonic bits
        key[i] = ((unsigned long long)vb << 32) | (uint32_t)(ATOT - ix[i]);
    }
    __syncthreads();

    for (int k = 0; k < KTOP; ++k) {
        unsigned long long bk = 0; int bs = -1;
        for (int i = lane; i < n; i += 64) {
            unsigned long long kk = key[i];
            if (kk > bk) { bk = kk; bs = i; }
        }
        #pragma unroll
        for (int sft = 32; sft > 0; sft >>= 1) {
            unsigned long long ok = __shfl_down(bk, sft);
            int os = __shfl_down(bs, sft);
            if (ok > bk) { bk = ok; bs = os; }
        }
        if (lane == 0) {
            int aa = ATOT - (int)(bk & 0xffffffffu);
            atomicOr(&mask[(size_t)b * ATOT + aa], bit);
            key[bs] = 0;                                     // remove winner
        }
        __syncthreads();
    }
}

// ---------------------------------------------------------------------------
// Phase 3: resolve multi-assignment by best IoU; block-reduce CE + count,
// one atomic pair per block; LAST block (done-ticket) writes the final output.
// ---------------------------------------------------------------------------
__global__ __launch_bounds__(256) void phase3_loss(
    const float* __restrict__ cls0, const float* __restrict__ reg0,
    const float* __restrict__ cls1, const float* __restrict__ reg1,
    const float* __restrict__ cls2, const float* __restrict__ reg2,
    const float* __restrict__ anchors, const float* __restrict__ gtb,
    const int* __restrict__ gtl,
    const uint32_t* __restrict__ mask, const float* __restrict__ logZ,
    float* __restrict__ lossAcc, int* __restrict__ cntAcc,
    int* __restrict__ done, float* __restrict__ out)
{
    int t = blockIdx.x * 256 + threadIdx.x;
    float ce = 0.f; int pc = 0;

    if (t < NB * ATOT) {
        int b = t / ATOT, a = t % ATOT;
        uint32_t mk = mask[(size_t)b * ATOT + a];
        if (mk) {
            const float* cls; const float* reg; int off, A; float stride;
            if (a < A0)           { cls = cls0; reg = reg0; off = 0;     A = A0; stride = 8.f;  }
            else if (a < A0 + A1) { cls = cls1; reg = reg1; off = A0;    A = A1; stride = 16.f; }
            else                  { cls = cls2; reg = reg2; off = A0+A1; A = A2; stride = 32.f; }
            int al = a - off;

            float ax = anchors[2 * a]     * stride;
            float ay = anchors[2 * a + 1] * stride;
            float4 rr = *reinterpret_cast<const float4*>(reg + ((size_t)b * A + al) * 4);
            float px1 = ax - rr.x * stride, py1 = ay - rr.y * stride;
            float px2 = ax + rr.z * stride, py2 = ay + rr.w * stride;
            float area1 = (px2 - px1) * (py2 - py1);

            const float4* gb4 = reinterpret_cast<const float4*>(gtb + (size_t)b * NG * 4);

            float bestI = -1.f; int bestG = 0;
            uint32_t mm = mk;
            while (mm) {
                int g = __ffs(mm) - 1; mm &= mm - 1;
                float4 gv = gb4[g];
                float ltx = fmaxf(px1, gv.x), lty = fmaxf(py1, gv.y);
                float rbx = fminf(px2, gv.z), rby = fminf(py2, gv.w);
                float w = fmaxf(rbx - ltx, 0.f), h = fmaxf(rby - lty, 0.f);
                float inter = w * h;
                float area2 = (gv.z - gv.x) * (gv.w - gv.y);
                float iou = inter / (area1 + area2 - inter + EPSF);
                if (iou > bestI) { bestI = iou; bestG = g; }   // ascending g: lowest on tie
            }
            int tl = gtl[b * NG + bestG];
            const float* crow = cls + ((size_t)b * A + al) * NCLS;
            ce = logZ[(size_t)b * ATOT + a] - crow[tl];        // -log_softmax[target]
            pc = 1;
        }
    }

    // wave-level reduce (64 lanes)
    #pragma unroll
    for (int sft = 32; sft > 0; sft >>= 1) {
        ce += __shfl_down(ce, sft);
        pc += __shfl_down(pc, sft);
    }
    __shared__ float sce[4];
    __shared__ int   spc[4];
    int wid = threadIdx.x >> 6, lane = threadIdx.x & 63;
    if (lane == 0) { sce[wid] = ce; spc[wid] = pc; }
    __syncthreads();
    if (threadIdx.x == 0) {
        float tce = sce[0] + sce[1] + sce[2] + sce[3];
        int   tpc = spc[0] + spc[1] + spc[2] + spc[3];
        if (tpc) {
            atomicAdd(lossAcc, tce);
            atomicAdd(cntAcc, tpc);
        }
        __threadfence();                         // publish before the ticket
        int prev = atomicAdd(done, 1);
        if (prev == (int)gridDim.x - 1) {        // last block: finalize
            // atomic-RMW reads: coherent across XCDs (plain loads could be stale)
            float total = atomicAdd(lossAcc, 0.f);
            int   n     = atomicAdd(cntAcc, 0);
            float denom = (float)(n < 1 ? 1 : n);
            out[0] = total / denom;
            out[1] = (float)n;
        }
    }
}

extern "C" void kernel_launch(void* const* d_in, const int* in_sizes, int n_in,
                              void* d_out, int out_size, void* d_ws, size_t ws_size,
                              hipStream_t stream)
{
    const float* cls0 = (const float*)d_in[0];
    const float* reg0 = (const float*)d_in[1];
    const float* cls1 = (const float*)d_in[2];
    const float* reg1 = (const float*)d_in[3];
    const float* cls2 = (const float*)d_in[4];
    const float* reg2 = (const float*)d_in[5];
    const float* anchors = (const float*)d_in[6];
    const float* gtb  = (const float*)d_in[7];
    const int*   gtl  = (const int*)d_in[8];

    // workspace layout
    float*    logZ    = (float*)d_ws;                              // NB*ATOT
    uint32_t* mask    = (uint32_t*)(logZ + (size_t)NB * ATOT);     // NB*ATOT
    int*      cnt     = (int*)(mask + (size_t)NB * ATOT);          // NB*NG*3
    float*    lossAcc = (float*)(cnt + NB * NG * 3);
    int*      cntAcc  = (int*)(lossAcc + 1);
    int*      done    = (int*)(cntAcc + 1);
    float*    cval    = (float*)(done + 1);                        // NB*NG*3*CAP
    int*      cidx    = (int*)(cval + (size_t)NB * NG * 3 * CAP);  // NB*NG*3*CAP

    int nthr = NB * ATOT;
    int nblk = (nthr + 255) / 256;
    init_small<<<1, 256, 0, stream>>>(cnt, lossAcc, cntAcc, done);
    phase1_metric<<<nblk, 256, 0, stream>>>(cls0, reg0, cls1, reg1, cls2, reg2,
                                            anchors, gtb, gtl, logZ, cnt, cval, cidx, mask);
    phase2_topk<<<NB * NG * 3, 64, 0, stream>>>(cnt, cval, cidx, mask);
    phase3_loss<<<nblk, 256, 0, stream>>>(cls0, reg0, cls1, reg1, cls2, reg2,
                                          anchors, gtb, gtl, mask, logZ,
                                          lossAcc, cntAcc, done, (float*)d_out);
}

// Round 5
// 48.831 us; speedup vs baseline: 1.7261x; 1.7261x over previous
//
#include <hip/hip_runtime.h>
#include <cstdint>
#include <cstddef>

#define NCLS 80
#define KTOP 10
#define NG   20
#define NB   32
#define A0   6400
#define A1   1600
#define A2   400
#define ATOT 8400
#define EPSF 1e-9f
#define CAP  512      // max in-box anchors per (b,g,level): boxes <=136px -> <=18^2=324

#define NTHR   (NB * ATOT)
#define NBLK3  ((NTHR + 255) / 256)   // phase3 grid = partials count

// ---------------------------------------------------------------------------
// Init: zero candidate counters. (mask zeroing folded into phase1; loss
// accumulation is contention-free partials now.)
// ---------------------------------------------------------------------------
__global__ __launch_bounds__(256) void init_small(int* __restrict__ cnt)
{
    for (int i = threadIdx.x; i < NB * NG * 3; i += 256) cnt[i] = 0;
}

// ---------------------------------------------------------------------------
// Phase 1: per (b, anchor): zero mask word; in-box test FIRST (cheap: reg +
// broadcast boxes); only anchors inside >=1 gt box load the 80-class row and
// do the softmax. Appends (val, a) candidates per (b,g,level) list.
// ---------------------------------------------------------------------------
__global__ __launch_bounds__(256) void phase1_metric(
    const float* __restrict__ cls0, const float* __restrict__ reg0,
    const float* __restrict__ cls1, const float* __restrict__ reg1,
    const float* __restrict__ cls2, const float* __restrict__ reg2,
    const float* __restrict__ anchors, const float* __restrict__ gtb,
    const int* __restrict__ gtl,
    float* __restrict__ logZ, int* __restrict__ cnt,
    float* __restrict__ cval, int* __restrict__ cidx,
    uint32_t* __restrict__ mask)
{
    int t = blockIdx.x * 256 + threadIdx.x;
    if (t >= NTHR) return;
    mask[t] = 0;                       // free coalesced zeroing (replaces 40us memset)
    int b = t / ATOT, a = t % ATOT;

    const float* cls; const float* reg; int off, A, lvl; float stride;
    if (a < A0)           { cls = cls0; reg = reg0; off = 0;     A = A0; lvl = 0; stride = 8.f;  }
    else if (a < A0 + A1) { cls = cls1; reg = reg1; off = A0;    A = A1; lvl = 1; stride = 16.f; }
    else                  { cls = cls2; reg = reg2; off = A0+A1; A = A2; lvl = 2; stride = 32.f; }
    int al = a - off;

    float ax = anchors[2 * a]     * stride;
    float ay = anchors[2 * a + 1] * stride;

    // in-box test over all 20 gts (broadcast loads, L1/L2 hit)
    const float4* gb4 = reinterpret_cast<const float4*>(gtb + (size_t)b * NG * 4);
    uint32_t ingMask = 0;
    #pragma unroll
    for (int g = 0; g < NG; ++g) {
        float4 gv = gb4[g];
        bool ing = (ax - gv.x > EPSF) && (ay - gv.y > EPSF) &&
                   (gv.z - ax > EPSF) && (gv.w - ay > EPSF);
        if (ing) ingMask |= (1u << g);
    }
    if (!ingMask) return;   // ~75% of anchors: skip the 320B cls row entirely

    // predicted box
    float4 rr = *reinterpret_cast<const float4*>(reg + ((size_t)b * A + al) * 4);
    float px1 = ax - rr.x * stride, py1 = ay - rr.y * stride;
    float px2 = ax + rr.z * stride, py2 = ay + rr.w * stride;
    float area1 = (px2 - px1) * (py2 - py1);

    // softmax stats: 20 aligned float4 loads, kept in registers
    const float* crow = cls + ((size_t)b * A + al) * NCLS;
    const float4* crow4 = reinterpret_cast<const float4*>(crow);
    float r[NCLS];
    float m = -1e30f;
    #pragma unroll
    for (int j = 0; j < NCLS / 4; ++j) {
        float4 v = crow4[j];
        r[4*j+0] = v.x; r[4*j+1] = v.y; r[4*j+2] = v.z; r[4*j+3] = v.w;
        m = fmaxf(m, fmaxf(fmaxf(v.x, v.y), fmaxf(v.z, v.w)));
    }
    float s = 0.f;
    #pragma unroll
    for (int c = 0; c < NCLS; ++c) s += __expf(r[c] - m);
    float lz = m + __logf(s);
    logZ[(size_t)b * ATOT + a] = lz;

    const int* gl = gtl + b * NG;

    uint32_t mm = ingMask;
    while (mm) {
        int g = __ffs(mm) - 1; mm &= mm - 1;
        float4 gv = gb4[g];
        float ltx = fmaxf(px1, gv.x), lty = fmaxf(py1, gv.y);
        float rbx = fminf(px2, gv.z), rby = fminf(py2, gv.w);
        float w = fmaxf(rbx - ltx, 0.f), h = fmaxf(rby - lty, 0.f);
        float inter = w * h;
        float area2 = (gv.z - gv.x) * (gv.w - gv.y);
        float iou = inter / (area1 + area2 - inter + EPSF);
        float sc = __expf(crow[gl[g]] - lz);      // softmax score at gt label (L1-hot row)
        float i2 = iou * iou;
        float met = sc * (i2 * i2 * i2);          // score^1 * iou^6
        if (met > EPSF) {
            int list = (b * NG + g) * 3 + lvl;
            int slot = atomicAdd(&cnt[list], 1);  // 1920 distinct counters: low contention
            if (slot < CAP) {
                cval[(size_t)list * CAP + slot] = met;
                cidx[(size_t)list * CAP + slot] = a;
            }
        }
    }
}

// ---------------------------------------------------------------------------
// Phase 2: exact top-10 per (b,g,level) over the compacted candidate list.
// Sort key = (val_bits << 32) | (ATOT - a): max key == (val desc, idx asc),
// identical tie-break to jax.lax.top_k. All candidates are > EPS by
// construction, so n<=KTOP means all are selected.
// ---------------------------------------------------------------------------
__global__ __launch_bounds__(64) void phase2_topk(
    const int* __restrict__ cnt, const float* __restrict__ cval,
    const int* __restrict__ cidx, uint32_t* __restrict__ mask)
{
    int id = blockIdx.x;            // (b*NG+g)*3 + lvl
    int bg = id / 3;
    int b = bg / NG, g = bg % NG;
    uint32_t bit = 1u << g;
    int lane = threadIdx.x;

    int n = cnt[id]; if (n > CAP) n = CAP;
    if (n == 0) return;

    const float* v  = cval + (size_t)id * CAP;
    const int*   ix = cidx + (size_t)id * CAP;

    if (n <= KTOP) {
        for (int i = lane; i < n; i += 64)
            atomicOr(&mask[(size_t)b * ATOT + ix[i]], bit);
        return;
    }

    __shared__ unsigned long long key[CAP];
    for (int i = lane; i < n; i += 64) {
        uint32_t vb = __float_as_uint(v[i]);                 // val > 0 -> monotonic bits
        key[i] = ((unsigned long long)vb << 32) | (uint32_t)(ATOT - ix[i]);
    }
    __syncthreads();

    for (int k = 0; k < KTOP; ++k) {
        unsigned long long bk = 0; int bs = -1;
        for (int i = lane; i < n; i += 64) {
            unsigned long long kk = key[i];
            if (kk > bk) { bk = kk; bs = i; }
        }
        #pragma unroll
        for (int sft = 32; sft > 0; sft >>= 1) {
            unsigned long long ok = __shfl_down(bk, sft);
            int os = __shfl_down(bs, sft);
            if (ok > bk) { bk = ok; bs = os; }
        }
        if (lane == 0) {
            int aa = ATOT - (int)(bk & 0xffffffffu);
            atomicOr(&mask[(size_t)b * ATOT + aa], bit);
            key[bs] = 0;                                     // remove winner
        }
        __syncthreads();
    }
}

// ---------------------------------------------------------------------------
// Phase 3: resolve multi-assignment by best IoU; block-reduce CE + count,
// write per-block partials to DISTINCT addresses (no atomics, no fences —
// the same-line atomic ping-pong was 47us of round 4).
// ---------------------------------------------------------------------------
__global__ __launch_bounds__(256) void phase3_loss(
    const float* __restrict__ cls0, const float* __restrict__ reg0,
    const float* __restrict__ cls1, const float* __restrict__ reg1,
    const float* __restrict__ cls2, const float* __restrict__ reg2,
    const float* __restrict__ anchors, const float* __restrict__ gtb,
    const int* __restrict__ gtl,
    const uint32_t* __restrict__ mask, const float* __restrict__ logZ,
    float2* __restrict__ partials)
{
    int t = blockIdx.x * 256 + threadIdx.x;
    float ce = 0.f; float pc = 0.f;

    if (t < NTHR) {
        int b = t / ATOT, a = t % ATOT;
        uint32_t mk = mask[(size_t)b * ATOT + a];
        if (mk) {
            const float* cls; const float* reg; int off, A; float stride;
            if (a < A0)           { cls = cls0; reg = reg0; off = 0;     A = A0; stride = 8.f;  }
            else if (a < A0 + A1) { cls = cls1; reg = reg1; off = A0;    A = A1; stride = 16.f; }
            else                  { cls = cls2; reg = reg2; off = A0+A1; A = A2; stride = 32.f; }
            int al = a - off;

            float ax = anchors[2 * a]     * stride;
            float ay = anchors[2 * a + 1] * stride;
            float4 rr = *reinterpret_cast<const float4*>(reg + ((size_t)b * A + al) * 4);
            float px1 = ax - rr.x * stride, py1 = ay - rr.y * stride;
            float px2 = ax + rr.z * stride, py2 = ay + rr.w * stride;
            float area1 = (px2 - px1) * (py2 - py1);

            const float4* gb4 = reinterpret_cast<const float4*>(gtb + (size_t)b * NG * 4);

            float bestI = -1.f; int bestG = 0;
            uint32_t mm = mk;
            while (mm) {
                int g = __ffs(mm) - 1; mm &= mm - 1;
                float4 gv = gb4[g];
                float ltx = fmaxf(px1, gv.x), lty = fmaxf(py1, gv.y);
                float rbx = fminf(px2, gv.z), rby = fminf(py2, gv.w);
                float w = fmaxf(rbx - ltx, 0.f), h = fmaxf(rby - lty, 0.f);
                float inter = w * h;
                float area2 = (gv.z - gv.x) * (gv.w - gv.y);
                float iou = inter / (area1 + area2 - inter + EPSF);
                if (iou > bestI) { bestI = iou; bestG = g; }   // ascending g: lowest on tie
            }
            int tl = gtl[b * NG + bestG];
            const float* crow = cls + ((size_t)b * A + al) * NCLS;
            ce = logZ[(size_t)b * ATOT + a] - crow[tl];        // -log_softmax[target]
            pc = 1.f;
        }
    }

    // wave-level reduce (64 lanes)
    #pragma unroll
    for (int sft = 32; sft > 0; sft >>= 1) {
        ce += __shfl_down(ce, sft);
        pc += __shfl_down(pc, sft);
    }
    __shared__ float sce[4];
    __shared__ float spc[4];
    int wid = threadIdx.x >> 6, lane = threadIdx.x & 63;
    if (lane == 0) { sce[wid] = ce; spc[wid] = pc; }
    __syncthreads();
    if (threadIdx.x == 0) {
        float2 p;
        p.x = sce[0] + sce[1] + sce[2] + sce[3];
        p.y = spc[0] + spc[1] + spc[2] + spc[3];
        partials[blockIdx.x] = p;        // distinct address per block: no contention
    }
}

// ---------------------------------------------------------------------------
// Finalize: single block reduces the per-block partials, writes output.
// ---------------------------------------------------------------------------
__global__ __launch_bounds__(256) void finalize_loss(
    const float2* __restrict__ partials, float* __restrict__ out)
{
    float ce = 0.f, pc = 0.f;
    for (int i = threadIdx.x; i < NBLK3; i += 256) {
        float2 p = partials[i];
        ce += p.x; pc += p.y;
    }
    #pragma unroll
    for (int sft = 32; sft > 0; sft >>= 1) {
        ce += __shfl_down(ce, sft);
        pc += __shfl_down(pc, sft);
    }
    __shared__ float sce[4];
    __shared__ float spc[4];
    int wid = threadIdx.x >> 6, lane = threadIdx.x & 63;
    if (lane == 0) { sce[wid] = ce; spc[wid] = pc; }
    __syncthreads();
    if (threadIdx.x == 0) {
        float total = sce[0] + sce[1] + sce[2] + sce[3];
        int   n     = (int)(spc[0] + spc[1] + spc[2] + spc[3]);
        float denom = (float)(n < 1 ? 1 : n);
        out[0] = total / denom;
        out[1] = (float)n;
    }
}

extern "C" void kernel_launch(void* const* d_in, const int* in_sizes, int n_in,
                              void* d_out, int out_size, void* d_ws, size_t ws_size,
                              hipStream_t stream)
{
    const float* cls0 = (const float*)d_in[0];
    const float* reg0 = (const float*)d_in[1];
    const float* cls1 = (const float*)d_in[2];
    const float* reg1 = (const float*)d_in[3];
    const float* cls2 = (const float*)d_in[4];
    const float* reg2 = (const float*)d_in[5];
    const float* anchors = (const float*)d_in[6];
    const float* gtb  = (const float*)d_in[7];
    const int*   gtl  = (const int*)d_in[8];

    // workspace layout
    float*    logZ     = (float*)d_ws;                              // NB*ATOT
    uint32_t* mask     = (uint32_t*)(logZ + (size_t)NB * ATOT);     // NB*ATOT
    int*      cnt      = (int*)(mask + (size_t)NB * ATOT);          // NB*NG*3
    float2*   partials = (float2*)(cnt + NB * NG * 3 + 2);          // NBLK3 float2 (8B aligned)
    float*    cval     = (float*)(partials + NBLK3);                // NB*NG*3*CAP
    int*      cidx     = (int*)(cval + (size_t)NB * NG * 3 * CAP);  // NB*NG*3*CAP

    init_small<<<1, 256, 0, stream>>>(cnt);
    phase1_metric<<<NBLK3, 256, 0, stream>>>(cls0, reg0, cls1, reg1, cls2, reg2,
                                             anchors, gtb, gtl, logZ, cnt, cval, cidx, mask);
    phase2_topk<<<NB * NG * 3, 64, 0, stream>>>(cnt, cval, cidx, mask);
    phase3_loss<<<NBLK3, 256, 0, stream>>>(cls0, reg0, cls1, reg1, cls2, reg2,
                                           anchors, gtb, gtl, mask, logZ, partials);
    finalize_loss<<<1, 256, 0, stream>>>(partials, (float*)d_out);
}

// Round 6
// 36.773 us; speedup vs baseline: 2.2921x; 1.3279x over previous
//
#include <hip/hip_runtime.h>
#include <cstdint>
#include <cstddef>

#define NCLS 80
#define KTOP 10
#define NG   20
#define NB   32
#define A0   6400
#define A1   1600
#define A2   400
#define ATOT 8400
#define EPSF 1e-9f

#define NTHR   (NB * ATOT)
#define NBLK   ((NTHR + 255) / 256)
#define RECTCAP 512   // max rect anchors per (b,g,lvl): boxes <=136px -> <=19x19=361

// ---------------------------------------------------------------------------
// Phase 1: per (b, anchor): zero mask word; in-box-any test (cheap: broadcast
// boxes); only anchors inside >=1 gt box do the 80-class softmax -> logZ.
// No candidate lists, no atomics (phase2 enumerates candidates analytically).
// ---------------------------------------------------------------------------
__global__ __launch_bounds__(256) void phase1_logz(
    const float* __restrict__ cls0, const float* __restrict__ cls1,
    const float* __restrict__ cls2,
    const float* __restrict__ anchors, const float* __restrict__ gtb,
    float* __restrict__ logZ, uint32_t* __restrict__ mask)
{
    int t = blockIdx.x * 256 + threadIdx.x;
    if (t >= NTHR) return;
    mask[t] = 0;                       // free coalesced zeroing (vs 40us memset)
    int b = t / ATOT, a = t % ATOT;

    const float* cls; int A; float stride;
    if (a < A0)           { cls = cls0; A = A0; stride = 8.f;  }
    else if (a < A0 + A1) { cls = cls1; A = A1; stride = 16.f; }
    else                  { cls = cls2; A = A2; stride = 32.f; }
    int al = (a < A0) ? a : (a < A0 + A1 ? a - A0 : a - A0 - A1);

    float ax = anchors[2 * a]     * stride;
    float ay = anchors[2 * a + 1] * stride;

    // in-box-any test over all 20 gts (broadcast loads, L1/L2 hit)
    const float4* gb4 = reinterpret_cast<const float4*>(gtb + (size_t)b * NG * 4);
    bool any = false;
    #pragma unroll
    for (int g = 0; g < NG; ++g) {
        float4 gv = gb4[g];
        any = any || ((ax - gv.x > EPSF) && (ay - gv.y > EPSF) &&
                      (gv.z - ax > EPSF) && (gv.w - ay > EPSF));
    }
    if (!any) return;   // ~75% of anchors: skip the 320B cls row entirely

    // softmax stats: 20 aligned float4 loads, kept in registers
    const float4* crow4 = reinterpret_cast<const float4*>(cls + ((size_t)b * A + al) * NCLS);
    float r[NCLS];
    float m = -1e30f;
    #pragma unroll
    for (int j = 0; j < NCLS / 4; ++j) {
        float4 v = crow4[j];
        r[4*j+0] = v.x; r[4*j+1] = v.y; r[4*j+2] = v.z; r[4*j+3] = v.w;
        m = fmaxf(m, fmaxf(fmaxf(v.x, v.y), fmaxf(v.z, v.w)));
    }
    float s = 0.f;
    #pragma unroll
    for (int c = 0; c < NCLS; ++c) s += __expf(r[c] - m);
    logZ[(size_t)b * ATOT + a] = m + __logf(s);
}

// ---------------------------------------------------------------------------
// Phase 2: per (b,g,level): enumerate the analytic in-box anchor rectangle
// (conservative bounds + bit-exact strict test), compute metric on the fly
// from logZ/cls/reg, exact top-10 with jax.lax.top_k tie-break
// (key = met_bits<<32 | (ATOT-a): val desc, idx asc). met<=EPS -> key 0.
// ---------------------------------------------------------------------------
__global__ __launch_bounds__(64) void phase2_topk(
    const float* __restrict__ cls0, const float* __restrict__ reg0,
    const float* __restrict__ cls1, const float* __restrict__ reg1,
    const float* __restrict__ cls2, const float* __restrict__ reg2,
    const float* __restrict__ gtb, const int* __restrict__ gtl,
    const float* __restrict__ logZ, uint32_t* __restrict__ mask)
{
    int id  = blockIdx.x;           // (b*NG+g)*3 + lvl
    int lvl = id % 3;
    int bg  = id / 3;
    int b = bg / NG, g = bg % NG;
    int lane = threadIdx.x;

    const float* cls; const float* reg; int off, A, W; float stride;
    if (lvl == 0)      { cls = cls0; reg = reg0; off = 0;     A = A0; W = 80; stride = 8.f;  }
    else if (lvl == 1) { cls = cls1; reg = reg1; off = A0;    A = A1; W = 40; stride = 16.f; }
    else               { cls = cls2; reg = reg2; off = A0+A1; A = A2; W = 20; stride = 32.f; }

    float4 gv = reinterpret_cast<const float4*>(gtb + (size_t)b * NG * 4)[g];
    int lbl = gtl[b * NG + g];

    // conservative rect (superset); exact strict test applied per anchor below
    float inv = 1.f / stride;
    int ix0 = max(0,     (int)floorf(gv.x * inv - 0.5f));
    int ix1 = min(W - 1, (int)ceilf (gv.z * inv - 0.5f));
    int iy0 = max(0,     (int)floorf(gv.y * inv - 0.5f));
    int iy1 = min(W - 1, (int)ceilf (gv.w * inv - 0.5f));
    int nx = ix1 - ix0 + 1, ny = iy1 - iy0 + 1;
    if (nx <= 0 || ny <= 0) return;
    int n = nx * ny; if (n > RECTCAP) n = RECTCAP;

    float area2 = (gv.z - gv.x) * (gv.w - gv.y);

    __shared__ unsigned long long key[RECTCAP];
    for (int i = lane; i < n; i += 64) {
        int iy = i / nx, ix = i - iy * nx;
        int gx = ix0 + ix, gy = iy0 + iy;
        float ax = ((float)gx + 0.5f) * stride;   // bit-identical to anchors[]*stride
        float ay = ((float)gy + 0.5f) * stride;
        unsigned long long kk = 0;
        bool ing = (ax - gv.x > EPSF) && (ay - gv.y > EPSF) &&
                   (gv.z - ax > EPSF) && (gv.w - ay > EPSF);
        if (ing) {
            int al = gy * W + gx;
            int a  = off + al;
            float4 rr = *reinterpret_cast<const float4*>(reg + ((size_t)b * A + al) * 4);
            float px1 = ax - rr.x * stride, py1 = ay - rr.y * stride;
            float px2 = ax + rr.z * stride, py2 = ay + rr.w * stride;
            float area1 = (px2 - px1) * (py2 - py1);
            float ltx = fmaxf(px1, gv.x), lty = fmaxf(py1, gv.y);
            float rbx = fminf(px2, gv.z), rby = fminf(py2, gv.w);
            float w = fmaxf(rbx - ltx, 0.f), h = fmaxf(rby - lty, 0.f);
            float inter = w * h;
            float iou = inter / (area1 + area2 - inter + EPSF);
            float lz = logZ[(size_t)b * ATOT + a];
            float c  = cls[((size_t)b * A + al) * NCLS + lbl];
            float sc = __expf(c - lz);                // softmax score at gt label
            float i2 = iou * iou;
            float met = sc * (i2 * i2 * i2);          // score^1 * iou^6
            if (met > EPSF)
                kk = ((unsigned long long)__float_as_uint(met) << 32)
                   | (uint32_t)(ATOT - a);
        }
        key[i] = kk;
    }
    __syncthreads();

    for (int k = 0; k < KTOP; ++k) {
        unsigned long long bk = 0; int bs = -1;
        for (int i = lane; i < n; i += 64) {
            unsigned long long kk = key[i];
            if (kk > bk) { bk = kk; bs = i; }         // keys unique (idx in low bits)
        }
        #pragma unroll
        for (int sft = 32; sft > 0; sft >>= 1) {
            unsigned long long ok = __shfl_down(bk, sft);
            int os = __shfl_down(bs, sft);
            if (ok > bk) { bk = ok; bs = os; }
        }
        bk = __shfl(bk, 0); bs = __shfl(bs, 0);       // uniform break decision
        if (bk == 0) break;                           // fewer than 10 valid: all taken
        if (lane == 0) {
            int aa = ATOT - (int)(bk & 0xffffffffu);
            atomicOr(&mask[(size_t)b * ATOT + aa], 1u << g);
            key[bs] = 0;                              // remove winner
        }
        __syncthreads();
    }
}

// ---------------------------------------------------------------------------
// Phase 3: resolve multi-assignment by best IoU; block-reduce CE + count,
// per-block partials to DISTINCT addresses (no atomics — round-4 lesson).
// ---------------------------------------------------------------------------
__global__ __launch_bounds__(256) void phase3_loss(
    const float* __restrict__ cls0, const float* __restrict__ reg0,
    const float* __restrict__ cls1, const float* __restrict__ reg1,
    const float* __restrict__ cls2, const float* __restrict__ reg2,
    const float* __restrict__ anchors, const float* __restrict__ gtb,
    const int* __restrict__ gtl,
    const uint32_t* __restrict__ mask, const float* __restrict__ logZ,
    float2* __restrict__ partials)
{
    int t = blockIdx.x * 256 + threadIdx.x;
    float ce = 0.f; float pc = 0.f;

    if (t < NTHR) {
        int b = t / ATOT, a = t % ATOT;
        uint32_t mk = mask[(size_t)b * ATOT + a];
        if (mk) {
            const float* cls; const float* reg; int off, A; float stride;
            if (a < A0)           { cls = cls0; reg = reg0; off = 0;     A = A0; stride = 8.f;  }
            else if (a < A0 + A1) { cls = cls1; reg = reg1; off = A0;    A = A1; stride = 16.f; }
            else                  { cls = cls2; reg = reg2; off = A0+A1; A = A2; stride = 32.f; }
            int al = a - off;

            float ax = anchors[2 * a]     * stride;
            float ay = anchors[2 * a + 1] * stride;
            float4 rr = *reinterpret_cast<const float4*>(reg + ((size_t)b * A + al) * 4);
            float px1 = ax - rr.x * stride, py1 = ay - rr.y * stride;
            float px2 = ax + rr.z * stride, py2 = ay + rr.w * stride;
            float area1 = (px2 - px1) * (py2 - py1);

            const float4* gb4 = reinterpret_cast<const float4*>(gtb + (size_t)b * NG * 4);

            float bestI = -1.f; int bestG = 0;
            uint32_t mm = mk;
            while (mm) {
                int g = __ffs(mm) - 1; mm &= mm - 1;
                float4 gv = gb4[g];
                float ltx = fmaxf(px1, gv.x), lty = fmaxf(py1, gv.y);
                float rbx = fminf(px2, gv.z), rby = fminf(py2, gv.w);
                float w = fmaxf(rbx - ltx, 0.f), h = fmaxf(rby - lty, 0.f);
                float inter = w * h;
                float area2 = (gv.z - gv.x) * (gv.w - gv.y);
                float iou = inter / (area1 + area2 - inter + EPSF);
                if (iou > bestI) { bestI = iou; bestG = g; }   // ascending g: lowest on tie
            }
            int tl = gtl[b * NG + bestG];
            const float* crow = cls + ((size_t)b * A + al) * NCLS;
            ce = logZ[(size_t)b * ATOT + a] - crow[tl];        // -log_softmax[target]
            pc = 1.f;
        }
    }

    #pragma unroll
    for (int sft = 32; sft > 0; sft >>= 1) {
        ce += __shfl_down(ce, sft);
        pc += __shfl_down(pc, sft);
    }
    __shared__ float sce[4];
    __shared__ float spc[4];
    int wid = threadIdx.x >> 6, lane = threadIdx.x & 63;
    if (lane == 0) { sce[wid] = ce; spc[wid] = pc; }
    __syncthreads();
    if (threadIdx.x == 0) {
        float2 p;
        p.x = sce[0] + sce[1] + sce[2] + sce[3];
        p.y = spc[0] + spc[1] + spc[2] + spc[3];
        partials[blockIdx.x] = p;        // distinct address per block: no contention
    }
}

// ---------------------------------------------------------------------------
// Finalize: single block reduces per-block partials, writes output.
// ---------------------------------------------------------------------------
__global__ __launch_bounds__(256) void finalize_loss(
    const float2* __restrict__ partials, float* __restrict__ out)
{
    float ce = 0.f, pc = 0.f;
    for (int i = threadIdx.x; i < NBLK; i += 256) {
        float2 p = partials[i];
        ce += p.x; pc += p.y;
    }
    #pragma unroll
    for (int sft = 32; sft > 0; sft >>= 1) {
        ce += __shfl_down(ce, sft);
        pc += __shfl_down(pc, sft);
    }
    __shared__ float sce[4];
    __shared__ float spc[4];
    int wid = threadIdx.x >> 6, lane = threadIdx.x & 63;
    if (lane == 0) { sce[wid] = ce; spc[wid] = pc; }
    __syncthreads();
    if (threadIdx.x == 0) {
        float total = sce[0] + sce[1] + sce[2] + sce[3];
        int   n     = (int)(spc[0] + spc[1] + spc[2] + spc[3]);
        float denom = (float)(n < 1 ? 1 : n);
        out[0] = total / denom;
        out[1] = (float)n;
    }
}

extern "C" void kernel_launch(void* const* d_in, const int* in_sizes, int n_in,
                              void* d_out, int out_size, void* d_ws, size_t ws_size,
                              hipStream_t stream)
{
    const float* cls0 = (const float*)d_in[0];
    const float* reg0 = (const float*)d_in[1];
    const float* cls1 = (const float*)d_in[2];
    const float* reg1 = (const float*)d_in[3];
    const float* cls2 = (const float*)d_in[4];
    const float* reg2 = (const float*)d_in[5];
    const float* anchors = (const float*)d_in[6];
    const float* gtb  = (const float*)d_in[7];
    const int*   gtl  = (const int*)d_in[8];

    // workspace layout (everything read is rewritten earlier in the same call)
    float*    logZ     = (float*)d_ws;                              // NB*ATOT
    uint32_t* mask     = (uint32_t*)(logZ + (size_t)NB * ATOT);     // NB*ATOT
    float2*   partials = (float2*)(mask + (size_t)NB * ATOT);       // NBLK float2

    phase1_logz<<<NBLK, 256, 0, stream>>>(cls0, cls1, cls2, anchors, gtb, logZ, mask);
    phase2_topk<<<NB * NG * 3, 64, 0, stream>>>(cls0, reg0, cls1, reg1, cls2, reg2,
                                                gtb, gtl, logZ, mask);
    phase3_loss<<<NBLK, 256, 0, stream>>>(cls0, reg0, cls1, reg1, cls2, reg2,
                                          anchors, gtb, gtl, mask, logZ, partials);
    finalize_loss<<<1, 256, 0, stream>>>(partials, (float*)d_out);
}